// Round 7
// baseline (284.605 us; speedup 1.0000x reference)
//
#include <hip/hip_runtime.h>
#include <hip/hip_fp16.h>

namespace {
constexpr int CS = 16;        // channels
constexpr int XS = 8, YS = 8, US = 256, VS = 256;
constexpr int CH_STRIDE = XS * YS * US * VS;               // 4,194,304 voxels
constexpr size_t NVOX = (size_t)CH_STRIDE;
constexpr size_t ATLAS_HALFS = NVOX * CS;                  // 67,108,864 halfs = 128 MiB
constexpr size_t DUAL_BYTES  = ATLAS_HALFS * 2 * 2;        // 256 MiB
constexpr size_t SINGLE_BYTES = ATLAS_HALFS * 2;           // 128 MiB

// ---- Kernel 1: repack [C,X,Y,U,V] f32 -> two fp16 atlases [X,Y,U,V,C] -----
// Copy A: voxel v at slot v.  Copy B: voxel v at slot (v+1)&255 (so v-pairs
// starting at ODD v are 64B-line-aligned in B). Each block = one full v-row.
__global__ __launch_bounds__(256) void transpose2_kernel(
    const float* __restrict__ inp, __half* __restrict__ wsA, __half* __restrict__ wsB)
{
    __shared__ float lds[CS][257];                 // +1 pad
    size_t base = (size_t)blockIdx.x * 256;        // one (x,y,u) row: v=0..255
    #pragma unroll
    for (int c = 0; c < CS; ++c)                   // coalesced 4B reads per c
        lds[c][threadIdx.x] = inp[(size_t)c * CH_STRIDE + base + threadIdx.x];
    __syncthreads();
    size_t obase = base * CS;                      // in halfs
    #pragma unroll
    for (int it = 0; it < 2; ++it) {
        int flat0 = (it * 256 + threadIdx.x) * 8;  // 8 halfs per store
        uint4 pk;
        uint* pw = &pk.x;
        #pragma unroll
        for (int j = 0; j < 4; ++j) {
            int f0 = flat0 + j * 2, f1 = f0 + 1;
            __half2 h = __floats2half2_rn(lds[f0 & 15][f0 >> 4],
                                          lds[f1 & 15][f1 >> 4]);
            pw[j] = *reinterpret_cast<uint*>(&h);
        }
        *reinterpret_cast<uint4*>(wsA + obase + flat0) = pk;
        // copy B: slot shift by one voxel = +16 halfs, cyclic within the row
        *reinterpret_cast<uint4*>(wsB + obase + ((flat0 + 16) & 4095)) = pk;
    }
}

// ---- Kernel 2: gather; pick atlas copy by parity of i3 ---------------------
__global__ __launch_bounds__(256) void gather_dual_kernel(
    const __half* __restrict__ tinA, const __half* __restrict__ tinB,
    const float* __restrict__ grid, float* __restrict__ out, int P)
{
    int p = blockIdx.x * 256 + threadIdx.x;
    if (p >= P) return;

    float4 g = reinterpret_cast<const float4*>(grid)[p];

    float c0 = (g.x + 1.0f) * 0.5f * (XS - 1);
    float c1 = (g.y + 1.0f) * 0.5f * (YS - 1);
    float c2 = (g.z + 1.0f) * 0.5f * (US - 1);
    float c3 = (g.w + 1.0f) * 0.5f * (VS - 1);

    float f0 = floorf(c0), f1 = floorf(c1), f2 = floorf(c2), f3 = floorf(c3);
    int i0 = (int)f0, i1 = (int)f1, i2 = (int)f2, i3 = (int)f3;
    float t0 = c0 - f0, t1 = c1 - f1, t2 = c2 - f2, t3 = c3 - f3;

    float w0[2], w1[2], w2[2], w3[2];
    int   q0[2], q1[2], q2[2], slot3[2];
    #pragma unroll
    for (int b = 0; b < 2; ++b) {
        int j;
        j = i0 + b; w0[b] = (b ? t0 : 1.0f - t0) * ((j >= 0 && j < XS) ? 1.0f : 0.0f); q0[b] = min(max(j, 0), XS - 1);
        j = i1 + b; w1[b] = (b ? t1 : 1.0f - t1) * ((j >= 0 && j < YS) ? 1.0f : 0.0f); q1[b] = min(max(j, 0), YS - 1);
        j = i2 + b; w2[b] = (b ? t2 : 1.0f - t2) * ((j >= 0 && j < US) ? 1.0f : 0.0f); q2[b] = min(max(j, 0), US - 1);
        j = i3 + b; w3[b] = (b ? t3 : 1.0f - t3) * ((j >= 0 && j < VS) ? 1.0f : 0.0f); slot3[b] = min(max(j, 0), VS - 1);
    }
    int parity = i3 & 1;                           // 1 -> use copy B
    const __half* atlas = parity ? tinB : tinA;
    if (parity) {
        slot3[0] = (slot3[0] + 1) & 255;
        slot3[1] = (slot3[1] + 1) & 255;
    }

    float a[16];
    #pragma unroll
    for (int i = 0; i < 16; ++i) a[i] = 0.0f;

    #pragma unroll
    for (int bx = 0; bx < 2; ++bx)
    #pragma unroll
    for (int by = 0; by < 2; ++by) {
        int   xy  = (q0[bx] * YS + q1[by]) << 16;           // * US*VS
        float wxy = w0[bx] * w1[by];
        #pragma unroll
        for (int bu = 0; bu < 2; ++bu) {
            int   xyu  = xy + (q2[bu] << 8);                // * VS
            float wxyu = wxy * w2[bu];
            #pragma unroll
            for (int bv = 0; bv < 2; ++bv) {
                int   vox = xyu + slot3[bv];
                float w   = wxyu * w3[bv];
                const uint4* cp = reinterpret_cast<const uint4*>(atlas) + (size_t)vox * 2;
                uint4 r0 = cp[0], r1 = cp[1];               // 16 halfs = 32 B (same 64B line as sibling)
                uint rr[8] = {r0.x, r0.y, r0.z, r0.w, r1.x, r1.y, r1.z, r1.w};
                #pragma unroll
                for (int j = 0; j < 8; ++j) {
                    float2 f = __half22float2(*reinterpret_cast<const __half2*>(&rr[j]));
                    a[2*j]     = fmaf(w, f.x, a[2*j]);
                    a[2*j + 1] = fmaf(w, f.y, a[2*j + 1]);
                }
            }
        }
    }

    #pragma unroll
    for (int c = 0; c < CS; ++c)
        __builtin_nontemporal_store(a[c], &out[(size_t)c * P + p]);
}

// ---- Kernel 1b/2b: single-atlas path (R6) if ws < 256 MiB ------------------
__global__ __launch_bounds__(256) void transpose_h_kernel(
    const float* __restrict__ inp, __half* __restrict__ ws)
{
    __shared__ float lds[CS][257];
    size_t base = (size_t)blockIdx.x * 256;
    #pragma unroll
    for (int c = 0; c < CS; ++c)
        lds[c][threadIdx.x] = inp[(size_t)c * CH_STRIDE + base + threadIdx.x];
    __syncthreads();
    size_t obase = base * CS;
    #pragma unroll
    for (int it = 0; it < 2; ++it) {
        int flat0 = (it * 256 + threadIdx.x) * 8;
        uint4 pk;
        uint* pw = &pk.x;
        #pragma unroll
        for (int j = 0; j < 4; ++j) {
            int f0 = flat0 + j * 2, f1 = f0 + 1;
            __half2 h = __floats2half2_rn(lds[f0 & 15][f0 >> 4],
                                          lds[f1 & 15][f1 >> 4]);
            pw[j] = *reinterpret_cast<uint*>(&h);
        }
        *reinterpret_cast<uint4*>(ws + obase + flat0) = pk;
    }
}

__global__ __launch_bounds__(256) void gather_h_kernel(
    const __half* __restrict__ tin, const float* __restrict__ grid,
    float* __restrict__ out, int P)
{
    int p = blockIdx.x * 256 + threadIdx.x;
    if (p >= P) return;
    float4 g = reinterpret_cast<const float4*>(grid)[p];
    float c0 = (g.x + 1.0f) * 0.5f * (XS - 1);
    float c1 = (g.y + 1.0f) * 0.5f * (YS - 1);
    float c2 = (g.z + 1.0f) * 0.5f * (US - 1);
    float c3 = (g.w + 1.0f) * 0.5f * (VS - 1);
    float f0 = floorf(c0), f1 = floorf(c1), f2 = floorf(c2), f3 = floorf(c3);
    int i0 = (int)f0, i1 = (int)f1, i2 = (int)f2, i3 = (int)f3;
    float t0 = c0 - f0, t1 = c1 - f1, t2 = c2 - f2, t3 = c3 - f3;
    float w0[2], w1[2], w2[2], w3[2];
    int   q0[2], q1[2], q2[2], q3[2];
    #pragma unroll
    for (int b = 0; b < 2; ++b) {
        int j;
        j = i0 + b; w0[b] = (b ? t0 : 1.0f - t0) * ((j >= 0 && j < XS) ? 1.0f : 0.0f); q0[b] = min(max(j, 0), XS - 1);
        j = i1 + b; w1[b] = (b ? t1 : 1.0f - t1) * ((j >= 0 && j < YS) ? 1.0f : 0.0f); q1[b] = min(max(j, 0), YS - 1);
        j = i2 + b; w2[b] = (b ? t2 : 1.0f - t2) * ((j >= 0 && j < US) ? 1.0f : 0.0f); q2[b] = min(max(j, 0), US - 1);
        j = i3 + b; w3[b] = (b ? t3 : 1.0f - t3) * ((j >= 0 && j < VS) ? 1.0f : 0.0f); q3[b] = min(max(j, 0), VS - 1);
    }
    float a[16];
    #pragma unroll
    for (int i = 0; i < 16; ++i) a[i] = 0.0f;
    #pragma unroll
    for (int bx = 0; bx < 2; ++bx)
    #pragma unroll
    for (int by = 0; by < 2; ++by) {
        int   xy  = (q0[bx] * YS + q1[by]) << 16;
        float wxy = w0[bx] * w1[by];
        #pragma unroll
        for (int bu = 0; bu < 2; ++bu) {
            int   xyu  = xy + (q2[bu] << 8);
            float wxyu = wxy * w2[bu];
            #pragma unroll
            for (int bv = 0; bv < 2; ++bv) {
                int   vox = xyu + q3[bv];
                float w   = wxyu * w3[bv];
                const uint4* cp = reinterpret_cast<const uint4*>(tin) + (size_t)vox * 2;
                uint4 r0 = cp[0], r1 = cp[1];
                uint rr[8] = {r0.x, r0.y, r0.z, r0.w, r1.x, r1.y, r1.z, r1.w};
                #pragma unroll
                for (int j = 0; j < 8; ++j) {
                    float2 f = __half22float2(*reinterpret_cast<const __half2*>(&rr[j]));
                    a[2*j]     = fmaf(w, f.x, a[2*j]);
                    a[2*j + 1] = fmaf(w, f.y, a[2*j + 1]);
                }
            }
        }
    }
    #pragma unroll
    for (int c = 0; c < CS; ++c)
        __builtin_nontemporal_store(a[c], &out[(size_t)c * P + p]);
}

// ---- Fallback (R2 kernel) if ws is too small -------------------------------
__global__ __launch_bounds__(256) void gs4d_fallback(
    const float* __restrict__ inp, const float* __restrict__ grid,
    float* __restrict__ out, int P)
{
    int p = blockIdx.x * 256 + threadIdx.x;
    if (p >= P) return;
    int c = blockIdx.y;
    float4 g = reinterpret_cast<const float4*>(grid)[p];
    float c0 = (g.x + 1.0f) * 0.5f * (XS - 1);
    float c1 = (g.y + 1.0f) * 0.5f * (YS - 1);
    float c2 = (g.z + 1.0f) * 0.5f * (US - 1);
    float c3 = (g.w + 1.0f) * 0.5f * (VS - 1);
    float f0 = floorf(c0), f1 = floorf(c1), f2 = floorf(c2), f3 = floorf(c3);
    int i0 = (int)f0, i1 = (int)f1, i2 = (int)f2, i3 = (int)f3;
    float t0 = c0 - f0, t1 = c1 - f1, t2 = c2 - f2, t3 = c3 - f3;
    float w0[2], w1[2], w2[2], w3[2];
    int   q0[2], q1[2], q2[2], q3[2];
    #pragma unroll
    for (int b = 0; b < 2; ++b) {
        int j;
        j = i0 + b; w0[b] = (b ? t0 : 1.0f - t0) * ((j >= 0 && j < XS) ? 1.0f : 0.0f); q0[b] = min(max(j, 0), XS - 1);
        j = i1 + b; w1[b] = (b ? t1 : 1.0f - t1) * ((j >= 0 && j < YS) ? 1.0f : 0.0f); q1[b] = min(max(j, 0), YS - 1);
        j = i2 + b; w2[b] = (b ? t2 : 1.0f - t2) * ((j >= 0 && j < US) ? 1.0f : 0.0f); q2[b] = min(max(j, 0), US - 1);
        j = i3 + b; w3[b] = (b ? t3 : 1.0f - t3) * ((j >= 0 && j < VS) ? 1.0f : 0.0f); q3[b] = min(max(j, 0), VS - 1);
    }
    const float* ip = inp + (size_t)c * CH_STRIDE;
    float acc = 0.0f;
    #pragma unroll
    for (int bx = 0; bx < 2; ++bx)
    #pragma unroll
    for (int by = 0; by < 2; ++by)
    #pragma unroll
    for (int bu = 0; bu < 2; ++bu)
    #pragma unroll
    for (int bv = 0; bv < 2; ++bv) {
        int idx = ((q0[bx] * YS + q1[by]) * US + q2[bu]) * VS + q3[bv];
        acc = fmaf(w0[bx] * w1[by] * w2[bu] * w3[bv], ip[idx], acc);
    }
    __builtin_nontemporal_store(acc, &out[(size_t)c * P + p]);
}
} // anonymous namespace

extern "C" void kernel_launch(void* const* d_in, const int* in_sizes, int n_in,
                              void* d_out, int out_size, void* d_ws, size_t ws_size,
                              hipStream_t stream) {
    const float* inp  = (const float*)d_in[0];   // [1,16,8,8,256,256] f32
    const float* grid = (const float*)d_in[1];   // [1,P,4] f32
    float* out = (float*)d_out;                  // [1,16,P] f32
    int P = in_sizes[1] / 4;
    int pblocks = (P + 255) / 256;

    if (ws_size >= DUAL_BYTES) {
        __half* wsA = (__half*)d_ws;
        __half* wsB = wsA + ATLAS_HALFS;
        transpose2_kernel<<<CH_STRIDE / 256, 256, 0, stream>>>(inp, wsA, wsB);
        gather_dual_kernel<<<pblocks, 256, 0, stream>>>(wsA, wsB, grid, out, P);
    } else if (ws_size >= SINGLE_BYTES) {
        __half* ws = (__half*)d_ws;
        transpose_h_kernel<<<CH_STRIDE / 256, 256, 0, stream>>>(inp, ws);
        gather_h_kernel<<<pblocks, 256, 0, stream>>>(ws, grid, out, P);
    } else {
        dim3 blocks(pblocks, CS);
        gs4d_fallback<<<blocks, 256, 0, stream>>>(inp, grid, out, P);
    }
}